// Round 4
// baseline (882.496 us; speedup 1.0000x reference)
//
#include <hip/hip_runtime.h>

#define B_     4
#define T_     4096
#define C_     1024
#define H_     4096
#define BT_    (B_ * T_)
#define NCH_   64
#define CHLEN_ 64
#define MCHUNK 4096   // rows per h-chunk for GEMM2a/2b

typedef __bf16 bf16_t;
typedef __bf16 bf16x8 __attribute__((ext_vector_type(8)));
typedef float  f32x4  __attribute__((ext_vector_type(4)));

__device__ __forceinline__ float hs_f(float v) {
    // clip(v+3, 0, 6)/6 - 0.5
    return fminf(fmaxf((v + 3.0f) * (1.0f / 6.0f), 0.0f), 1.0f) - 0.5f;
}

__device__ __forceinline__ void gld_lds16(const bf16_t* g, bf16_t* l) {
    __builtin_amdgcn_global_load_lds((const __attribute__((address_space(1))) void*)g,
                                     (__attribute__((address_space(3))) void*)l,
                                     16, 0, 0);
}

// ---------------------------------------------------------------------------
// inv_rms per row (f32 input): inv[row] = rsqrt(mean(x^2)+1e-6).
// 1 wave per row, 4 rows/block, float4 loads.
// ---------------------------------------------------------------------------
__global__ __launch_bounds__(256) void rms_rows_f32(const float* __restrict__ X,
                                                    float* __restrict__ inv) {
    const int wave = threadIdx.x >> 6, lane = threadIdx.x & 63;
    const int row = blockIdx.x * 4 + wave;
    const float* xr = X + (size_t)row * C_;
    float s = 0.0f;
    #pragma unroll
    for (int p = 0; p < 4; p++) {
        float4 v = *(const float4*)(xr + p * 256 + lane * 4);
        s += v.x * v.x + v.y * v.y + v.z * v.z + v.w * v.w;
    }
    #pragma unroll
    for (int o = 32; o > 0; o >>= 1) s += __shfl_down(s, o, 64);
    if (lane == 0) inv[row] = rsqrtf(s * (1.0f / C_) + 1e-6f);
}

// Same, bf16 input (for the "out" buffer).
__global__ __launch_bounds__(256) void rms_rows_bf16(const bf16_t* __restrict__ X,
                                                     float* __restrict__ inv) {
    const int wave = threadIdx.x >> 6, lane = threadIdx.x & 63;
    const int row = blockIdx.x * 4 + wave;
    const bf16_t* xr = X + (size_t)row * C_;
    bf16x8 v0 = *(const bf16x8*)(xr + lane * 8);
    bf16x8 v1 = *(const bf16x8*)(xr + 512 + lane * 8);
    float s = 0.0f;
    #pragma unroll
    for (int j = 0; j < 8; j++) {
        float a = (float)v0[j], b = (float)v1[j];
        s += a * a + b * b;
    }
    #pragma unroll
    for (int o = 32; o > 0; o >>= 1) s += __shfl_down(s, o, 64);
    if (lane == 0) inv[row] = rsqrtf(s * (1.0f / C_) + 1e-6f);
}

// ---------------------------------------------------------------------------
// Scan pass 1: per-chunk sums of g = hs(rmsnorm(x)) along t. f32 input.
// grid=(B_*NCH_, C_/256), block=256.
// ---------------------------------------------------------------------------
__global__ __launch_bounds__(256) void scan_chunksum(const float* __restrict__ X,
                                                     const float* __restrict__ inv1,
                                                     const float* __restrict__ nw,
                                                     float* __restrict__ csum) {
    const int bch = blockIdx.x;            // b*64 + ch
    const int b = bch >> 6, ch = bch & 63;
    const int c = blockIdx.y * 256 + threadIdx.x;
    const float wgt = nw[c];
    const int rbase = b * T_ + ch * CHLEN_;
    const size_t base = (size_t)rbase * C_ + c;
    float acc = 0.0f;
    for (int i = 0; i < CHLEN_; i++)
        acc += hs_f(X[base + (size_t)i * C_] * inv1[rbase + i] * wgt);
    csum[(size_t)bch * C_ + c] = acc;
}

// ---------------------------------------------------------------------------
// Scan pass 2: exclusive scan of chunk sums along ch, per (b, c).
// ---------------------------------------------------------------------------
__global__ __launch_bounds__(256) void scan_offsets(float* __restrict__ csum) {
    const int idx = blockIdx.x * 256 + threadIdx.x;   // b*1024 + c
    const int b = idx >> 10, c = idx & 1023;
    const size_t base = (size_t)b * NCH_ * C_ + c;
    float run = 0.0f;
    for (int ch = 0; ch < NCH_; ch++) {
        const float t = csum[base + (size_t)ch * C_];
        csum[base + (size_t)ch * C_] = run;
        run += t;
    }
}

// ---------------------------------------------------------------------------
// Scan pass 3: recompute prefix + offset; emit state as bf16 hi/lo pair into
// a 16384 x 2048 matrix: [0:1024) = hi, [1024:2048) = lo.
// ---------------------------------------------------------------------------
__global__ __launch_bounds__(256) void scan_emit(const float* __restrict__ X,
                                                 const float* __restrict__ inv1,
                                                 const float* __restrict__ nw,
                                                 const float* __restrict__ csum,
                                                 bf16_t* __restrict__ state) {
    const int bch = blockIdx.x;
    const int b = bch >> 6, ch = bch & 63;
    const int c = blockIdx.y * 256 + threadIdx.x;
    const float wgt = nw[c];
    const int rbase = b * T_ + ch * CHLEN_;
    const size_t xbase = (size_t)rbase * C_ + c;
    float acc = csum[(size_t)bch * C_ + c];   // exclusive chunk offset
    for (int i = 0; i < CHLEN_; i++) {
        acc += hs_f(X[xbase + (size_t)i * C_] * inv1[rbase + i] * wgt);
        const size_t srow = (size_t)(rbase + i) * 2048 + c;
        const bf16_t hi = (bf16_t)acc;
        state[srow] = hi;
        state[srow + 1024] = (bf16_t)(acc - (float)hi);   // residual
    }
}

// ---------------------------------------------------------------------------
// Transpose f32 -> bf16 (+optional per-source-row scale, +optional duplicate
// write at k+dupOff): dst[n*ldd + k (+dupOff)] = bf16(src[k*N+n]*scale[k]).
// grid=(N/32, K/32), block=256.
// ---------------------------------------------------------------------------
__global__ __launch_bounds__(256) void transpose_scale(const float* __restrict__ src,
                                                       bf16_t* __restrict__ dst,
                                                       int K, int N, int ldd, int dupOff,
                                                       const float* __restrict__ scale) {
    __shared__ float tile[32][33];
    const int n0 = blockIdx.x * 32, k0 = blockIdx.y * 32;
    const int tx = threadIdx.x & 31, ty = threadIdx.x >> 5;  // ty in 0..7
    #pragma unroll
    for (int j = 0; j < 4; j++) {
        const int kk = ty + j * 8;
        float v = src[(size_t)(k0 + kk) * N + n0 + tx];
        if (scale) v *= scale[k0 + kk];
        tile[kk][tx] = v;
    }
    __syncthreads();
    #pragma unroll
    for (int j = 0; j < 4; j++) {
        const int nn = ty + j * 8;
        const bf16_t v = (bf16_t)tile[tx][nn];
        dst[(size_t)(n0 + nn) * ldd + k0 + tx] = v;
        if (dupOff) dst[(size_t)(n0 + nn) * ldd + dupOff + k0 + tx] = v;
    }
}

// ---------------------------------------------------------------------------
// bf16 MFMA GEMM, acc = A(MxK) * Bt(NxK)^T, 128x128 tile, BK=32, 4 waves.
// m97-style staging: global_load_lds width=16 (async DMA, no VGPR round-trip).
// MODE 0: out bf16 = hs(acc + bias[n]) * xf32[m*N+n]            (GEMM1)
// MODE 1: out bf16 = relu(rowscale[m]*acc + bias[n])            (GEMM2a)
// MODE 2: out f32  = acc + bias[n] + (f32)extra_bf16[m*N+n]     (GEMM2b)
// ---------------------------------------------------------------------------
template <int MODE, typename ET, typename OT>
__global__ __launch_bounds__(256) void gemm_bt(const bf16_t* __restrict__ A,
                                               const bf16_t* __restrict__ Bt,
                                               const float* __restrict__ bias,
                                               const ET* __restrict__ extra,
                                               const float* __restrict__ rowscale,
                                               OT* __restrict__ Cmat,
                                               int N, int K) {
    __shared__ __align__(16) bf16_t As[128 * 32];
    __shared__ __align__(16) bf16_t Bs[128 * 32];
    const int tid = threadIdx.x;
    const int mBase = blockIdx.x * 128;
    const int nBase = blockIdx.y * 128;
    const int wave = tid >> 6;
    const int lane = tid & 63;
    const int waveM = (wave & 1) * 64;
    const int waveN = (wave >> 1) * 64;
    const int lr = lane & 15;   // A row (m) / B row (n) within frag
    const int lq = lane >> 4;   // quad -> k-group of 8

    f32x4 acc[4][4] = {};

    // staging geometry: elem offset e = j*2048 + tid*8 in a 128x32 row-major tile.
    // LDS dest per wave = wave-uniform base + lane*16B (global_load_lds contract).
    const int e0 = tid * 8;
    const int r0 = e0 >> 5, c0 = e0 & 31;
    const int e1 = 2048 + tid * 8;
    const int r1 = e1 >> 5, c1 = e1 & 31;

    const bf16_t* Ag0 = A + (size_t)(mBase + r0) * K + c0;
    const bf16_t* Ag1 = A + (size_t)(mBase + r1) * K + c1;
    const bf16_t* Bg0 = Bt + (size_t)(nBase + r0) * K + c0;
    const bf16_t* Bg1 = Bt + (size_t)(nBase + r1) * K + c1;

    for (int kb = 0; kb < K; kb += 32) {
        __syncthreads();  // previous tile's ds_reads done before overwrite
        gld_lds16(Ag0 + kb, As + e0);
        gld_lds16(Ag1 + kb, As + e1);
        gld_lds16(Bg0 + kb, Bs + e0);
        gld_lds16(Bg1 + kb, Bs + e1);
        __syncthreads();  // compiler drains vmcnt before barrier: staging visible

        bf16x8 af[4], bfr[4];
        #pragma unroll
        for (int mi = 0; mi < 4; mi++)
            af[mi] = *(const bf16x8*)(As + (waveM + mi * 16 + lr) * 32 + lq * 8);
        #pragma unroll
        for (int ni = 0; ni < 4; ni++)
            bfr[ni] = *(const bf16x8*)(Bs + (waveN + ni * 16 + lr) * 32 + lq * 8);
        #pragma unroll
        for (int mi = 0; mi < 4; mi++)
            #pragma unroll
            for (int ni = 0; ni < 4; ni++)
                acc[mi][ni] = __builtin_amdgcn_mfma_f32_16x16x32_bf16(
                    af[mi], bfr[ni], acc[mi][ni], 0, 0, 0);
    }

    // Epilogue. C/D layout (m89/m91-verified): col(n)=lane&15, row(m)=(lane>>4)*4+reg.
    #pragma unroll
    for (int ni = 0; ni < 4; ni++) {
        const int n = nBase + waveN + ni * 16 + lr;
        const float bz = bias[n];
        #pragma unroll
        for (int mi = 0; mi < 4; mi++) {
            #pragma unroll
            for (int r = 0; r < 4; r++) {
                const int m = mBase + waveM + mi * 16 + lq * 4 + r;
                float v = acc[mi][ni][r];
                if (MODE == 0) {
                    v = hs_f(v + bz) * (float)extra[(size_t)m * N + n];
                } else if (MODE == 1) {
                    v = fmaxf(rowscale[m] * v + bz, 0.0f);
                } else {
                    v = v + bz + (float)extra[(size_t)m * N + n];
                }
                Cmat[(size_t)m * N + n] = (OT)v;
            }
        }
    }
}

// ---------------------------------------------------------------------------
extern "C" void kernel_launch(void* const* d_in, const int* in_sizes, int n_in,
                              void* d_out, int out_size, void* d_ws, size_t ws_size,
                              hipStream_t stream) {
    const float* x   = (const float*)d_in[0];  // B,T,C
    const float* n1w = (const float*)d_in[1];  // C
    const float* w1  = (const float*)d_in[2];  // C,C
    const float* b1  = (const float*)d_in[3];  // C
    const float* n2w = (const float*)d_in[4];  // C
    const float* w2a = (const float*)d_in[5];  // C,H
    const float* b2a = (const float*)d_in[6];  // H
    const float* w2b = (const float*)d_in[7];  // H,C
    const float* b2b = (const float*)d_in[8];  // C
    float* y = (float*)d_out;                  // B,T,C f32

    // Workspace layout (total ~117.1 MiB):
    char* w = (char*)d_ws;
    float*  inv1  = (float*)(w + 0);            //  64 KB
    float*  inv2  = (float*)(w + 65536);        //  64 KB
    float*  csum  = (float*)(w + 131072);       //   1 MB (256 x 1024 f32)
    bf16_t* W1cat = (bf16_t*)(w + 1179648);     //   4 MB (1024 x 2048, dup halves)
    bf16_t* W2at  = (bf16_t*)(w + 5373952);     //   8 MB (n2w folded in)
    bf16_t* W2bt  = (bf16_t*)(w + 13762560);    //   8 MB
    bf16_t* outb  = (bf16_t*)(w + 22151168);    //  32 MB (live to the end)
    bf16_t* state = (bf16_t*)(w + 55705600);    //  64 MB (16384 x [hi|lo])
    bf16_t* hbuf  = state;                      //  h chunks (state dead after GEMM1)

    // 1) inv_rms of x rows
    rms_rows_f32<<<dim3(BT_ / 4), dim3(256), 0, stream>>>(x, inv1);
    // 2) chunked cumsum of hard_sigmoid(rmsnorm(x)) -> bf16 hi/lo state
    scan_chunksum<<<dim3(B_ * NCH_, C_ / 256), dim3(256), 0, stream>>>(x, inv1, n1w, csum);
    scan_offsets<<<dim3(B_ * C_ / 256), dim3(256), 0, stream>>>(csum);
    scan_emit<<<dim3(B_ * NCH_, C_ / 256), dim3(256), 0, stream>>>(x, inv1, n1w, csum, state);
    // 3) weight transposes: W1 duplicated into both K-halves; n2w folded into W2a
    transpose_scale<<<dim3(C_ / 32, C_ / 32), dim3(256), 0, stream>>>(
        w1, W1cat, C_, C_, 2048, 1024, nullptr);
    transpose_scale<<<dim3(H_ / 32, C_ / 32), dim3(256), 0, stream>>>(
        w2a, W2at, C_, H_, C_, 0, n2w);
    transpose_scale<<<dim3(C_ / 32, H_ / 32), dim3(256), 0, stream>>>(
        w2b, W2bt, H_, C_, H_, 0, nullptr);
    // 4) GEMM1 (K=2048, hi/lo): out = hs(state@W1 + b1) * x   -> bf16
    gemm_bt<0, float, bf16_t><<<dim3(BT_ / 128, C_ / 128), dim3(256), 0, stream>>>(
        state, W1cat, b1, x, nullptr, outb, C_, 2048);
    // 5) inv_rms of out rows
    rms_rows_bf16<<<dim3(BT_ / 4), dim3(256), 0, stream>>>(outb, inv2);
    // 6/7) chunked: h = relu(inv2[m]*(out@(n2w*W2a)) + b2a); y = h@W2b + b2b + out
    for (int c = 0; c < BT_ / MCHUNK; c++) {
        const bf16_t* Ao = outb + (size_t)c * MCHUNK * C_;
        float* yo = y + (size_t)c * MCHUNK * C_;
        gemm_bt<1, float, bf16_t><<<dim3(MCHUNK / 128, H_ / 128), dim3(256), 0, stream>>>(
            Ao, W2at, b2a, nullptr, inv2 + c * MCHUNK, hbuf, H_, C_);
        gemm_bt<2, bf16_t, float><<<dim3(MCHUNK / 128, C_ / 128), dim3(256), 0, stream>>>(
            hbuf, W2bt, b2b, Ao, nullptr, yo, C_, H_);
    }
}

// Round 5
// 720.370 us; speedup vs baseline: 1.2251x; 1.2251x over previous
//
#include <hip/hip_runtime.h>

#define B_     4
#define T_     4096
#define C_     1024
#define H_     4096
#define BT_    (B_ * T_)
#define NCH_   64
#define CHLEN_ 64
#define MCHUNK 8192   // rows per h-chunk for GEMM2a/2b (2 chunks)

typedef __bf16 bf16_t;
typedef __bf16 bf16x8 __attribute__((ext_vector_type(8)));
typedef float  f32x4  __attribute__((ext_vector_type(4)));

__device__ __forceinline__ float hs_f(float v) {
    // clip(v+3, 0, 6)/6 - 0.5
    return fminf(fmaxf((v + 3.0f) * (1.0f / 6.0f), 0.0f), 1.0f) - 0.5f;
}

__device__ __forceinline__ void gld_lds16(const bf16_t* g, bf16_t* l) {
    __builtin_amdgcn_global_load_lds((const __attribute__((address_space(1))) void*)g,
                                     (__attribute__((address_space(3))) void*)l,
                                     16, 0, 0);
}

// ---------------------------------------------------------------------------
// inv_rms per row (f32 input): inv[row] = rsqrt(mean(x^2)+1e-6).
// ---------------------------------------------------------------------------
__global__ __launch_bounds__(256) void rms_rows_f32(const float* __restrict__ X,
                                                    float* __restrict__ inv) {
    const int wave = threadIdx.x >> 6, lane = threadIdx.x & 63;
    const int row = blockIdx.x * 4 + wave;
    const float* xr = X + (size_t)row * C_;
    float s = 0.0f;
    #pragma unroll
    for (int p = 0; p < 4; p++) {
        float4 v = *(const float4*)(xr + p * 256 + lane * 4);
        s += v.x * v.x + v.y * v.y + v.z * v.z + v.w * v.w;
    }
    #pragma unroll
    for (int o = 32; o > 0; o >>= 1) s += __shfl_down(s, o, 64);
    if (lane == 0) inv[row] = rsqrtf(s * (1.0f / C_) + 1e-6f);
}

// Same, bf16 input (for the "out" buffer).
__global__ __launch_bounds__(256) void rms_rows_bf16(const bf16_t* __restrict__ X,
                                                     float* __restrict__ inv) {
    const int wave = threadIdx.x >> 6, lane = threadIdx.x & 63;
    const int row = blockIdx.x * 4 + wave;
    const bf16_t* xr = X + (size_t)row * C_;
    bf16x8 v0 = *(const bf16x8*)(xr + lane * 8);
    bf16x8 v1 = *(const bf16x8*)(xr + 512 + lane * 8);
    float s = 0.0f;
    #pragma unroll
    for (int j = 0; j < 8; j++) {
        float a = (float)v0[j], b = (float)v1[j];
        s += a * a + b * b;
    }
    #pragma unroll
    for (int o = 32; o > 0; o >>= 1) s += __shfl_down(s, o, 64);
    if (lane == 0) inv[row] = rsqrtf(s * (1.0f / C_) + 1e-6f);
}

// ---------------------------------------------------------------------------
// Scan pass 1: per-chunk sums of g = hs(rmsnorm(x)) along t.
// grid=(B_*NCH_, C_/256), block=256.
// ---------------------------------------------------------------------------
__global__ __launch_bounds__(256) void scan_chunksum(const float* __restrict__ X,
                                                     const float* __restrict__ inv1,
                                                     const float* __restrict__ nw,
                                                     float* __restrict__ csum) {
    const int bch = blockIdx.x;            // b*64 + ch
    const int b = bch >> 6, ch = bch & 63;
    const int c = blockIdx.y * 256 + threadIdx.x;
    const float wgt = nw[c];
    const int rbase = b * T_ + ch * CHLEN_;
    const size_t base = (size_t)rbase * C_ + c;
    float acc = 0.0f;
    for (int i = 0; i < CHLEN_; i++)
        acc += hs_f(X[base + (size_t)i * C_] * inv1[rbase + i] * wgt);
    csum[(size_t)bch * C_ + c] = acc;
}

// ---------------------------------------------------------------------------
// Scan pass 2: exclusive scan of chunk sums along ch per (b,c); emit the
// exclusive offsets directly as a bf16 hi/lo matrix (256 x [hi|lo] 2048).
// ---------------------------------------------------------------------------
__global__ __launch_bounds__(256) void scan_offsets_hilo(const float* __restrict__ csum,
                                                         bf16_t* __restrict__ hilo) {
    const int idx = blockIdx.x * 256 + threadIdx.x;   // b*1024 + c
    const int b = idx >> 10, c = idx & 1023;
    const size_t base = (size_t)b * NCH_ * C_ + c;
    float run = 0.0f;
    for (int ch = 0; ch < NCH_; ch++) {
        const size_t row = (size_t)(b * NCH_ + ch) * 2048 + c;
        const bf16_t hi = (bf16_t)run;
        hilo[row] = hi;
        hilo[row + 1024] = (bf16_t)(run - (float)hi);
        run += csum[base + (size_t)ch * C_];
    }
}

// ---------------------------------------------------------------------------
// Scan pass 3: within-chunk inclusive prefix ONLY (starts at 0), emit bf16.
// The chunk offset is added later via the P matrix in GEMM1's epilogue.
// ---------------------------------------------------------------------------
__global__ __launch_bounds__(256) void scan_emit_local(const float* __restrict__ X,
                                                       const float* __restrict__ inv1,
                                                       const float* __restrict__ nw,
                                                       bf16_t* __restrict__ state) {
    const int bch = blockIdx.x;
    const int b = bch >> 6, ch = bch & 63;
    const int c = blockIdx.y * 256 + threadIdx.x;
    const float wgt = nw[c];
    const int rbase = b * T_ + ch * CHLEN_;
    const size_t xbase = (size_t)rbase * C_ + c;
    float acc = 0.0f;
    for (int i = 0; i < CHLEN_; i++) {
        acc += hs_f(X[xbase + (size_t)i * C_] * inv1[rbase + i] * wgt);
        state[(size_t)(rbase + i) * C_ + c] = (bf16_t)acc;
    }
}

// ---------------------------------------------------------------------------
// Transpose f32 -> bf16 (+optional per-source-row scale, +optional duplicate
// write at k+dupOff): dst[n*ldd + k (+dupOff)] = bf16(src[k*N+n]*scale[k]).
// ---------------------------------------------------------------------------
__global__ __launch_bounds__(256) void transpose_scale(const float* __restrict__ src,
                                                       bf16_t* __restrict__ dst,
                                                       int K, int N, int ldd, int dupOff,
                                                       const float* __restrict__ scale) {
    __shared__ float tile[32][33];
    const int n0 = blockIdx.x * 32, k0 = blockIdx.y * 32;
    const int tx = threadIdx.x & 31, ty = threadIdx.x >> 5;
    #pragma unroll
    for (int j = 0; j < 4; j++) {
        const int kk = ty + j * 8;
        float v = src[(size_t)(k0 + kk) * N + n0 + tx];
        if (scale) v *= scale[k0 + kk];
        tile[kk][tx] = v;
    }
    __syncthreads();
    #pragma unroll
    for (int j = 0; j < 4; j++) {
        const int nn = ty + j * 8;
        const bf16_t v = (bf16_t)tile[tx][nn];
        dst[(size_t)(n0 + nn) * ldd + k0 + tx] = v;
        if (dupOff) dst[(size_t)(n0 + nn) * ldd + dupOff + k0 + tx] = v;
    }
}

// ---------------------------------------------------------------------------
// bf16 MFMA GEMM, acc = A(MxK) * Bt(NxK)^T, 128x128 tile, BK=32, 4 waves.
// MODE 0: out bf16 = hs(acc + pmat[(m>>6)*N+n]) * xf32[m*N+n]   (GEMM1)
// MODE 1: out bf16 = relu(rowscale[m]*acc + bias[n])            (GEMM2a)
// MODE 2: out f32  = acc + bias[n] + (f32)extra_bf16[m*N+n]     (GEMM2b)
// MODE 3: out f32  = acc + bias[n]                              (P-GEMM)
// ---------------------------------------------------------------------------
template <int MODE, typename ET, typename OT>
__global__ __launch_bounds__(256) void gemm_bt(const bf16_t* __restrict__ A,
                                               const bf16_t* __restrict__ Bt,
                                               const float* __restrict__ bias,
                                               const ET* __restrict__ extra,
                                               const float* __restrict__ rowscale,
                                               const float* __restrict__ pmat,
                                               OT* __restrict__ Cmat,
                                               int N, int K) {
    __shared__ __align__(16) bf16_t As[128 * 32];
    __shared__ __align__(16) bf16_t Bs[128 * 32];
    const int tid = threadIdx.x;
    const int mBase = blockIdx.x * 128;
    const int nBase = blockIdx.y * 128;
    const int wave = tid >> 6;
    const int lane = tid & 63;
    const int waveM = (wave & 1) * 64;
    const int waveN = (wave >> 1) * 64;
    const int lr = lane & 15;   // A row (m) / B row (n) within frag
    const int lq = lane >> 4;   // quad -> k-group of 8

    f32x4 acc[4][4] = {};

    const int e0 = tid * 8;
    const int r0 = e0 >> 5, c0 = e0 & 31;
    const int e1 = 2048 + tid * 8;
    const int r1 = e1 >> 5, c1 = e1 & 31;

    const bf16_t* Ag0 = A + (size_t)(mBase + r0) * K + c0;
    const bf16_t* Ag1 = A + (size_t)(mBase + r1) * K + c1;
    const bf16_t* Bg0 = Bt + (size_t)(nBase + r0) * K + c0;
    const bf16_t* Bg1 = Bt + (size_t)(nBase + r1) * K + c1;

    for (int kb = 0; kb < K; kb += 32) {
        __syncthreads();
        gld_lds16(Ag0 + kb, As + e0);
        gld_lds16(Ag1 + kb, As + e1);
        gld_lds16(Bg0 + kb, Bs + e0);
        gld_lds16(Bg1 + kb, Bs + e1);
        __syncthreads();

        bf16x8 af[4], bfr[4];
        #pragma unroll
        for (int mi = 0; mi < 4; mi++)
            af[mi] = *(const bf16x8*)(As + (waveM + mi * 16 + lr) * 32 + lq * 8);
        #pragma unroll
        for (int ni = 0; ni < 4; ni++)
            bfr[ni] = *(const bf16x8*)(Bs + (waveN + ni * 16 + lr) * 32 + lq * 8);
        #pragma unroll
        for (int mi = 0; mi < 4; mi++)
            #pragma unroll
            for (int ni = 0; ni < 4; ni++)
                acc[mi][ni] = __builtin_amdgcn_mfma_f32_16x16x32_bf16(
                    af[mi], bfr[ni], acc[mi][ni], 0, 0, 0);
    }

    // Epilogue. C/D layout: col(n)=lane&15, row(m)=(lane>>4)*4+reg.
    #pragma unroll
    for (int ni = 0; ni < 4; ni++) {
        const int n = nBase + waveN + ni * 16 + lr;
        const float bz = (MODE == 0) ? 0.0f : bias[n];
        #pragma unroll
        for (int mi = 0; mi < 4; mi++) {
            #pragma unroll
            for (int r = 0; r < 4; r++) {
                const int m = mBase + waveM + mi * 16 + lq * 4 + r;
                float v = acc[mi][ni][r];
                if (MODE == 0) {
                    v = hs_f(v + pmat[(size_t)(m >> 6) * N + n]) * (float)extra[(size_t)m * N + n];
                } else if (MODE == 1) {
                    v = fmaxf(rowscale[m] * v + bz, 0.0f);
                } else if (MODE == 2) {
                    v = v + bz + (float)extra[(size_t)m * N + n];
                } else {
                    v = v + bz;
                }
                Cmat[(size_t)m * N + n] = (OT)v;
            }
        }
    }
}

// ---------------------------------------------------------------------------
extern "C" void kernel_launch(void* const* d_in, const int* in_sizes, int n_in,
                              void* d_out, int out_size, void* d_ws, size_t ws_size,
                              hipStream_t stream) {
    const float* x   = (const float*)d_in[0];  // B,T,C
    const float* n1w = (const float*)d_in[1];  // C
    const float* w1  = (const float*)d_in[2];  // C,C
    const float* b1  = (const float*)d_in[3];  // C
    const float* n2w = (const float*)d_in[4];  // C
    const float* w2a = (const float*)d_in[5];  // C,H
    const float* b2a = (const float*)d_in[6];  // H
    const float* w2b = (const float*)d_in[7];  // H,C
    const float* b2b = (const float*)d_in[8];  // C
    float* y = (float*)d_out;                  // B,T,C f32

    // Workspace layout (total ~121.1 MiB):
    char* w = (char*)d_ws;
    float*  inv1  = (float*)(w + 0);            //  64 KB
    float*  inv2  = (float*)(w + 65536);        //  64 KB
    float*  csum  = (float*)(w + 131072);       //   1 MB (256x1024 f32)
    bf16_t* hilo  = (bf16_t*)(w + 1179648);     //   1 MB (256x[hi|lo]2048 bf16)
    float*  Pmat  = (float*)(w + 2228224);      //   1 MB (256x1024 f32)
    bf16_t* W1t   = (bf16_t*)(w + 3276800);     //   2 MB (1024x1024)
    bf16_t* W1cat = (bf16_t*)(w + 5373952);     //   4 MB (1024x2048, dup halves)
    bf16_t* W2at  = (bf16_t*)(w + 9568256);     //   8 MB (n2w folded in)
    bf16_t* W2bt  = (bf16_t*)(w + 17956864);    //   8 MB
    bf16_t* outb  = (bf16_t*)(w + 26345472);    //  32 MB (live to the end)
    bf16_t* state = (bf16_t*)(w + 59899904);    //  32 MB (local prefixes)
    bf16_t* hbuf  = state;                      //  64 MB region (state dead after GEMM1)

    // 1) inv_rms of x rows
    rms_rows_f32<<<dim3(BT_ / 4), dim3(256), 0, stream>>>(x, inv1);
    // 2) chunk sums -> exclusive offsets (bf16 hi/lo); local prefixes -> state
    scan_chunksum<<<dim3(B_ * NCH_, C_ / 256), dim3(256), 0, stream>>>(x, inv1, n1w, csum);
    scan_offsets_hilo<<<dim3(B_ * C_ / 256), dim3(256), 0, stream>>>(csum, hilo);
    scan_emit_local<<<dim3(B_ * NCH_, C_ / 256), dim3(256), 0, stream>>>(x, inv1, n1w, state);
    // 3) weight transposes
    transpose_scale<<<dim3(C_ / 32, C_ / 32), dim3(256), 0, stream>>>(
        w1, W1t, C_, C_, 1024, 0, nullptr);
    transpose_scale<<<dim3(C_ / 32, C_ / 32), dim3(256), 0, stream>>>(
        w1, W1cat, C_, C_, 2048, 1024, nullptr);
    transpose_scale<<<dim3(H_ / 32, C_ / 32), dim3(256), 0, stream>>>(
        w2a, W2at, C_, H_, C_, 0, n2w);
    transpose_scale<<<dim3(C_ / 32, H_ / 32), dim3(256), 0, stream>>>(
        w2b, W2bt, H_, C_, H_, 0, nullptr);
    // 4) P = offsets @ W1 + b1  (hi/lo, K=2048, M=256)
    gemm_bt<3, float, float><<<dim3(2, C_ / 128), dim3(256), 0, stream>>>(
        hilo, W1cat, b1, nullptr, nullptr, nullptr, Pmat, C_, 2048);
    // 5) GEMM1 (K=1024): out = hs(local@W1 + P[chunk]) * x -> bf16
    gemm_bt<0, float, bf16_t><<<dim3(BT_ / 128, C_ / 128), dim3(256), 0, stream>>>(
        state, W1t, nullptr, x, nullptr, Pmat, outb, C_, C_);
    // 6) inv_rms of out rows
    rms_rows_bf16<<<dim3(BT_ / 4), dim3(256), 0, stream>>>(outb, inv2);
    // 7/8) chunked: h = relu(inv2[m]*(out@(n2w*W2a)) + b2a); y = h@W2b + b2b + out
    for (int c = 0; c < BT_ / MCHUNK; c++) {
        const bf16_t* Ao = outb + (size_t)c * MCHUNK * C_;
        float* yo = y + (size_t)c * MCHUNK * C_;
        gemm_bt<1, float, bf16_t><<<dim3(MCHUNK / 128, H_ / 128), dim3(256), 0, stream>>>(
            Ao, W2at, b2a, nullptr, inv2 + c * MCHUNK, nullptr, hbuf, H_, C_);
        gemm_bt<2, bf16_t, float><<<dim3(MCHUNK / 128, C_ / 128), dim3(256), 0, stream>>>(
            hbuf, W2bt, b2b, Ao, nullptr, nullptr, yo, C_, H_);
    }
}